// Round 5
// baseline (432.172 us; speedup 1.0000x reference)
//
#include <hip/hip_runtime.h>
#include <hip/hip_bf16.h>

typedef __attribute__((ext_vector_type(8))) __bf16 bf16x8;
typedef __attribute__((ext_vector_type(8))) short  short8;
typedef __attribute__((ext_vector_type(4))) float  f32x4;

// Problem constants
#define NIMG   64         // batch
#define FOUTC  128        // output channels
#define KTOT   2048       // 8*8*32
#define BK     64         // K per step
#define NSTEP  32         // 2048/64

// LDS byte offsets within one 48KB step-buffer
#define A_HI   0          // [64 rows n][64 k] bf16 hi  (8 KB)
#define A_LO   8192
#define B_HI   16384      // [128 rows o][64 k] bf16 hi (16 KB), k-transposed
#define B_LO   32768
#define BUFSZ  49152

// XOR swizzle: 16-B slot index ^= (row & 7). Same involution on write & read.
// Audit: every wave-wide LDS op (A/B x read/write) covers each of the 32
// banks exactly 8x per 1024B instruction -> zero excess conflicts.
__device__ __forceinline__ int addrA(int row, int slot) {
  return row * 128 + (((slot ^ row) & 7) << 4);
}
__device__ __forceinline__ int addrB(int o, int slot) {
  return o * 128 + (((slot ^ o) & 7) << 4);
}

// fp32 -> (hi, lo) bf16 split; hi + lo represents f to ~2^-17 relative.
__device__ __forceinline__ void cvt2(float f, short& h, short& l) {
  __hip_bfloat16 bh = __float2bfloat16(f);
  float fh = __bfloat162float(bh);
  __hip_bfloat16 bl = __float2bfloat16(f - fh);
  h = (short)__builtin_bit_cast(unsigned short, bh);
  l = (short)__builtin_bit_cast(unsigned short, bl);
}

struct StageRegs {
  float4 a0, a1;   // 8 consecutive k of one A row
  float  b[16];    // two k-slots (8 k each) of one filter column o
};

// Issue all global loads for K-step kb (fully coalesced; no waiting here).
__device__ __forceinline__ void issue_loads(const float* __restrict__ X,
                                            const float* __restrict__ F,
                                            int kb, int t, int p, int r, int c,
                                            StageRegs& R) {
  // ---- A: thread t -> row n = t>>3, k-slot = t&7 (8 consecutive k) ----
  // k = kb*64 + kk maps to X flat offset n*524288 + r*32768 + (kb>>2)*4096
  //   + c*256 + (kb&3)*64 + kk  (contiguous in kk across two adjacent w cols)
  const int n = t >> 3, slot = t & 7;
  const int arow = r * 32768 + (kb >> 2) * 4096 + c * 256 + (kb & 3) * 64;
  const float* ap = X + n * 524288 + arow + slot * 8;
  R.a0 = *(const float4*)(ap);
  R.a1 = *(const float4*)(ap + 4);
  // ---- B: thread t -> column o = t&127, slot-group sg = t>>7 ({sg, sg+4}) ----
  const int o = t & 127, sg = t >> 7;
  const float* bp = F + p * 262144 + kb * 8192 + o;
#pragma unroll
  for (int h = 0; h < 2; ++h) {
    const int ks = sg + h * 4;
#pragma unroll
    for (int j = 0; j < 8; ++j)
      R.b[h * 8 + j] = bp[(ks * 8 + j) * 128];   // 64 lanes x consecutive o = 256B coalesced
  }
}

// Convert staged regs to split-bf16 and write into LDS buffer `buf`.
__device__ __forceinline__ void stage_write(char* buf, int t, const StageRegs& R) {
  const int n = t >> 3, slot = t & 7;
  float av[8];
  av[0] = R.a0.x; av[1] = R.a0.y; av[2] = R.a0.z; av[3] = R.a0.w;
  av[4] = R.a1.x; av[5] = R.a1.y; av[6] = R.a1.z; av[7] = R.a1.w;
  short8 h, l;
#pragma unroll
  for (int e = 0; e < 8; ++e) { short hh, ll; cvt2(av[e], hh, ll); h[e] = hh; l[e] = ll; }
  const int aoff = addrA(n, slot);
  *(short8*)(buf + A_HI + aoff) = h;
  *(short8*)(buf + A_LO + aoff) = l;

  const int o = t & 127, sg = t >> 7;
#pragma unroll
  for (int hh2 = 0; hh2 < 2; ++hh2) {
    const int ks = sg + hh2 * 4;
    short8 bh, bl;
#pragma unroll
    for (int j = 0; j < 8; ++j) { short x, y; cvt2(R.b[hh2 * 8 + j], x, y); bh[j] = x; bl[j] = y; }
    const int boff = addrB(o, ks);
    *(short8*)(buf + B_HI + boff) = bh;
    *(short8*)(buf + B_LO + boff) = bl;
  }
}

// One K-step of MFMAs (K=64 => 2 x K32), split-bf16: hh + hl + lh.
// A frag (16x16x32): lane l holds row (l&15), k = (l>>4)*8 + e.
// B frag: lane l holds col (l&15), same k mapping; LDS B is [o][k].
__device__ __forceinline__ void mfma_step(const char* buf, int wm, int wn, int lane,
                                          f32x4 acc[4]) {
  const int arow = wm * 16 + (lane & 15);
  const int grp = lane >> 4;
#pragma unroll
  for (int ks = 0; ks < 2; ++ks) {
    const int slot = grp + ks * 4;
    const int aoff = addrA(arow, slot);
    bf16x8 ah = *(const bf16x8*)(buf + A_HI + aoff);
    bf16x8 al = *(const bf16x8*)(buf + A_LO + aoff);
#pragma unroll
    for (int nf = 0; nf < 4; ++nf) {
      const int o = wn * 64 + nf * 16 + (lane & 15);
      const int boff = addrB(o, slot);
      bf16x8 bh = *(const bf16x8*)(buf + B_HI + boff);
      bf16x8 bl = *(const bf16x8*)(buf + B_LO + boff);
      acc[nf] = __builtin_amdgcn_mfma_f32_16x16x32_bf16(ah, bh, acc[nf], 0, 0, 0);
      acc[nf] = __builtin_amdgcn_mfma_f32_16x16x32_bf16(ah, bl, acc[nf], 0, 0, 0);
      acc[nf] = __builtin_amdgcn_mfma_f32_16x16x32_bf16(al, bh, acc[nf], 0, 0, 0);
    }
  }
}

__global__ __launch_bounds__(512, 2)
void bioconv_kernel(const float* __restrict__ X, const float* __restrict__ F,
                    const float* __restrict__ bias, float* __restrict__ out) {
  __shared__ __align__(16) char lds[2 * BUFSZ];   // 96 KB -> 1 block/CU
  const int p = blockIdx.x;
  const int r = p >> 4, c = p & 15;
  const int t = threadIdx.x;
  const int lane = t & 63;
  const int w = t >> 6;
  const int wm = w & 3;   // 4 M-blocks of 16 rows  -> 64 rows (n)
  const int wn = w >> 2;  // 2 N-blocks of 64 cols  -> 128 cols (o)

  f32x4 acc[4] = {f32x4{0,0,0,0}, f32x4{0,0,0,0}, f32x4{0,0,0,0}, f32x4{0,0,0,0}};

  StageRegs Ra, Rb;
  // Prologue: stage tile 0, prefetch tile 1
  issue_loads(X, F, 0, t, p, r, c, Ra);
  stage_write(lds, t, Ra);
  issue_loads(X, F, 1, t, p, r, c, Rb);
  __syncthreads();

  for (int kb = 0; kb < NSTEP; kb += 2) {
    // half A: compute tile kb (buf0), prefetch kb+2, stage kb+1 -> buf1
    mfma_step(lds, wm, wn, lane, acc);
    if (kb + 2 < NSTEP) issue_loads(X, F, kb + 2, t, p, r, c, Ra);
    stage_write(lds + BUFSZ, t, Rb);
    __syncthreads();
    // half B: compute tile kb+1 (buf1), prefetch kb+3, stage kb+2 -> buf0
    mfma_step(lds + BUFSZ, wm, wn, lane, acc);
    if (kb + 3 < NSTEP) issue_loads(X, F, kb + 3, t, p, r, c, Rb);
    if (kb + 2 < NSTEP) stage_write(lds, t, Ra);
    __syncthreads();
  }

  // Epilogue: bias + relu + store. C/D layout: col = lane&15, row = (lane>>4)*4 + j
  const int colb = wn * 64 + (lane & 15);
  const int rowb = wm * 16 + (lane >> 4) * 4;
#pragma unroll
  for (int nf = 0; nf < 4; ++nf) {
    const int col = colb + nf * 16;
    const float bv = bias[col];
#pragma unroll
    for (int j = 0; j < 4; ++j) {
      float v = acc[nf][j] + bv;
      v = fmaxf(v, 0.0f);
      out[(rowb + j) * 32768 + p * 128 + col] = v;
    }
  }
}

extern "C" void kernel_launch(void* const* d_in, const int* in_sizes, int n_in,
                              void* d_out, int out_size, void* d_ws, size_t ws_size,
                              hipStream_t stream) {
  const float* X    = (const float*)d_in[0];  // [64,128,128,32]
  const float* F    = (const float*)d_in[1];  // [256,8,8,32,128]
  const float* bias = (const float*)d_in[2];  // [128]
  float* out = (float*)d_out;                 // [64,16,16,128]
  hipLaunchKernelGGL(bioconv_kernel, dim3(256), dim3(512), 0, stream, X, F, bias, out);
}